// Round 6
// baseline (144.978 us; speedup 1.0000x reference)
//
#include <hip/hip_runtime.h>
#include <hip/hip_bf16.h>

typedef __attribute__((ext_vector_type(8))) short bf16x8;
typedef __attribute__((ext_vector_type(4))) float f32x4;

#define NWIN 49
#define NH 8
#define CCH 256
#define PROW 72   // ushort stride for P rows (144B, 16B-aligned)

__device__ __forceinline__ ushort2 pk_bf16(float a, float b) {
    __hip_bfloat162 t = __float22bfloat162_rn(float2{a, b});   // v_cvt_pk_bf16_f32 (RNE)
    return *(ushort2*)&t;
}
__device__ __forceinline__ float upk(ushort u) { return __uint_as_float((unsigned)u << 16); }

// --- Kernel A: pos MLP table, (169, 8) fp32 ---
__global__ void pos_mlp_kernel(const float* __restrict__ W1, const float* __restrict__ b1,
                               const float* __restrict__ W2, const float* __restrict__ b2,
                               float* __restrict__ pos) {
    int idx = blockIdx.x * blockDim.x + threadIdx.x;
    if (idx >= 169) return;
    float bh = (float)(idx / 13) - 6.0f;
    float bw = (float)(idx % 13) - 6.0f;
    float outv[NH];
#pragma unroll
    for (int t = 0; t < NH; ++t) outv[t] = b2[t];
    for (int u = 0; u < 64; ++u) {
        float hv = fmaf(bh, W1[u], fmaf(bw, W1[64 + u], b1[u]));
        hv = fmaxf(hv, 0.0f);
#pragma unroll
        for (int t = 0; t < NH; ++t) outv[t] = fmaf(hv, W2[u * NH + t], outv[t]);
    }
#pragma unroll
    for (int t = 0; t < NH; ++t) pos[idx * NH + t] = outv[t];
}

// --- Kernel B: bias (×log2e) in S^T MFMA C/D fragment layout, -1e30 mask for j>=49 ---
// bfrag[((h*4 + jt)*4 + it)*256 + lane*4 + r] = log2e*bias(i=it*16+(lane&15), j=jt*16+(lane>>4)*4+r)
__global__ void bias_frag_kernel(const float* __restrict__ pos, float* __restrict__ bfrag) {
    int blk = blockIdx.x;           // ((h*4 + jt)*4 + it), 128 blocks
    int it = blk & 3, jt = (blk >> 2) & 3, h = blk >> 4;
    int lane = threadIdx.x;
    int g = lane >> 4, l15 = lane & 15;
    int i = it * 16 + l15;
    float4 v;
    float* vp = (float*)&v;
#pragma unroll
    for (int r = 0; r < 4; ++r) {
        int j = jt * 16 + g * 4 + r;
        float val;
        if (j >= NWIN) val = -1e30f;                       // exp2 -> 0
        else if (i >= NWIN) val = 0.0f;
        else {
            int rel = (i / 7 - j / 7 + 6) * 13 + (i % 7 - j % 7 + 6);
            val = pos[rel * NH + h] * 1.4426950408889634f; // fold log2e
        }
        vp[r] = val;
    }
    *(float4*)(bfrag + (size_t)blk * 256 + lane * 4) = v;
}

// --- Kernel C: 1 wave per (window, head); ALL loads issued before any compute ---
__global__ __launch_bounds__(64, 2) void attn_kernel(
    const float* __restrict__ q, const float* __restrict__ k,
    const float* __restrict__ v, const float* __restrict__ bfrag,
    float* __restrict__ out) {
    __shared__ __align__(16) ushort sP[64 * PROW];   // 9216 B, only LDS use

    const int blk = blockIdx.x;
    const int b = blk >> 3, h = blk & 7;
    const int lane = threadIdx.x & 63;
    const int g = lane >> 4, l15 = lane & 15;
    const size_t base = (size_t)b * (NWIN * CCH) + h * 32;

    // ======== Phase 0: issue ALL global loads up front (single stall window) ========
    float4 kraw[4][2], qraw[4][2];
#pragma unroll
    for (int t = 0; t < 4; ++t) {
        int row = t * 16 + l15;
        kraw[t][0] = (float4){0, 0, 0, 0}; kraw[t][1] = (float4){0, 0, 0, 0};
        qraw[t][0] = (float4){0, 0, 0, 0}; qraw[t][1] = (float4){0, 0, 0, 0};
        if (row < NWIN) {
            const float* kp = k + base + (size_t)row * CCH + g * 8;
            const float* qp = q + base + (size_t)row * CCH + g * 8;
            kraw[t][0] = *(const float4*)kp; kraw[t][1] = *(const float4*)(kp + 4);
            qraw[t][0] = *(const float4*)qp; qraw[t][1] = *(const float4*)(qp + 4);
        }
    }
    f32x4 bb[4][4];   // [jt][it] bias fragments (L2-hot table)
#pragma unroll
    for (int jt = 0; jt < 4; ++jt)
#pragma unroll
        for (int it = 0; it < 4; ++it)
            bb[jt][it] = *(const f32x4*)(bfrag + (size_t)((h * 4 + jt) * 4 + it) * 256 + lane * 4);
    float vraw[2][2][8];   // V B-frag elements (rows j=ks*32+g*8+e, col d=nt*16+l15)
#pragma unroll
    for (int ks = 0; ks < 2; ++ks)
#pragma unroll
        for (int nt = 0; nt < 2; ++nt)
#pragma unroll
            for (int e = 0; e < 8; ++e) {
                int j = ks * 32 + g * 8 + e;
                vraw[ks][nt][e] = (j < NWIN) ? v[base + (size_t)j * CCH + nt * 16 + l15] : 0.0f;
            }

    // ======== Phase 1: convert Q/K to bf16 hi+lo fragments ========
    bf16x8 kah[4], kal[4], qbh[4], qbl[4];
#pragma unroll
    for (int t = 0; t < 4; ++t) {
        float4 ka = kraw[t][0], kb = kraw[t][1];
        float4 qa = qraw[t][0], qb = qraw[t][1];
        ushort2 kh0 = pk_bf16(ka.x, ka.y), kh1 = pk_bf16(ka.z, ka.w);
        ushort2 kh2 = pk_bf16(kb.x, kb.y), kh3 = pk_bf16(kb.z, kb.w);
        ushort2 kl0 = pk_bf16(ka.x - upk(kh0.x), ka.y - upk(kh0.y));
        ushort2 kl1 = pk_bf16(ka.z - upk(kh1.x), ka.w - upk(kh1.y));
        ushort2 kl2 = pk_bf16(kb.x - upk(kh2.x), kb.y - upk(kh2.y));
        ushort2 kl3 = pk_bf16(kb.z - upk(kh3.x), kb.w - upk(kh3.y));
        ushort tkh[8] = {kh0.x, kh0.y, kh1.x, kh1.y, kh2.x, kh2.y, kh3.x, kh3.y};
        ushort tkl[8] = {kl0.x, kl0.y, kl1.x, kl1.y, kl2.x, kl2.y, kl3.x, kl3.y};
        kah[t] = *(bf16x8*)tkh; kal[t] = *(bf16x8*)tkl;
        ushort2 qh0 = pk_bf16(qa.x, qa.y), qh1 = pk_bf16(qa.z, qa.w);
        ushort2 qh2 = pk_bf16(qb.x, qb.y), qh3 = pk_bf16(qb.z, qb.w);
        ushort2 ql0 = pk_bf16(qa.x - upk(qh0.x), qa.y - upk(qh0.y));
        ushort2 ql1 = pk_bf16(qa.z - upk(qh1.x), qa.w - upk(qh1.y));
        ushort2 ql2 = pk_bf16(qb.x - upk(qh2.x), qb.y - upk(qh2.y));
        ushort2 ql3 = pk_bf16(qb.z - upk(qh3.x), qb.w - upk(qh3.y));
        ushort tqh[8] = {qh0.x, qh0.y, qh1.x, qh1.y, qh2.x, qh2.y, qh3.x, qh3.y};
        ushort tql[8] = {ql0.x, ql0.y, ql1.x, ql1.y, ql2.x, ql2.y, ql3.x, ql3.y};
        qbh[t] = *(bf16x8*)tqh; qbl[t] = *(bf16x8*)tql;
    }

    // ======== Phase 2: QK^T (swapped) — acc[jt][it] = S^T tile, bf16x3 ========
    f32x4 acc[4][4];
#pragma unroll
    for (int jt = 0; jt < 4; ++jt)
#pragma unroll
        for (int it = 0; it < 4; ++it) {
            f32x4 a = {0.f, 0.f, 0.f, 0.f};
            a = __builtin_amdgcn_mfma_f32_16x16x32_bf16(kah[jt], qbh[it], a, 0, 0, 0);
            a = __builtin_amdgcn_mfma_f32_16x16x32_bf16(kah[jt], qbl[it], a, 0, 0, 0);
            a = __builtin_amdgcn_mfma_f32_16x16x32_bf16(kal[jt], qbh[it], a, 0, 0, 0);
            acc[jt][it] = a;
        }

    // ======== Phase 3: softmax per column i (bias already in regs; no max-sub) ========
    const float scale2 = 0.17677669529663687f * 1.4426950408889634f;
#pragma unroll
    for (int it = 0; it < 4; ++it) {
        float p[16];
        float s = 0.0f;
#pragma unroll
        for (int jt = 0; jt < 4; ++jt)
#pragma unroll
            for (int r = 0; r < 4; ++r) {
                float e = __builtin_amdgcn_exp2f(fmaf(acc[jt][it][r], scale2, bb[jt][it][r]));
                p[jt * 4 + r] = e;
                s += e;
            }
        s += __shfl_xor(s, 16);
        s += __shfl_xor(s, 32);
        const float inv = 1.0f / s;
#pragma unroll
        for (int jt = 0; jt < 4; ++jt) {
            ushort2 a01 = pk_bf16(p[jt * 4 + 0] * inv, p[jt * 4 + 1] * inv);
            ushort2 a23 = pk_bf16(p[jt * 4 + 2] * inv, p[jt * 4 + 3] * inv);
            ushort4 w4; w4.x = a01.x; w4.y = a01.y; w4.z = a23.x; w4.w = a23.y;
            *(ushort4*)&sP[(it * 16 + l15) * PROW + jt * 16 + g * 4] = w4;
        }
    }

    // ======== Phase 4: pack V (arrived long ago) + PV ========
    bf16x8 bv[2][2];
#pragma unroll
    for (int ks = 0; ks < 2; ++ks)
#pragma unroll
        for (int nt = 0; nt < 2; ++nt) {
            ushort2 p0 = pk_bf16(vraw[ks][nt][0], vraw[ks][nt][1]);
            ushort2 p1 = pk_bf16(vraw[ks][nt][2], vraw[ks][nt][3]);
            ushort2 p2 = pk_bf16(vraw[ks][nt][4], vraw[ks][nt][5]);
            ushort2 p3 = pk_bf16(vraw[ks][nt][6], vraw[ks][nt][7]);
            ushort tv[8] = {p0.x, p0.y, p1.x, p1.y, p2.x, p2.y, p3.x, p3.y};
            bv[ks][nt] = *(bf16x8*)tv;
        }

    f32x4 oacc[4][2];
#pragma unroll
    for (int mt = 0; mt < 4; ++mt)
#pragma unroll
        for (int nt = 0; nt < 2; ++nt) oacc[mt][nt] = (f32x4){0.f, 0.f, 0.f, 0.f};
#pragma unroll
    for (int ks = 0; ks < 2; ++ks)
#pragma unroll
        for (int mt = 0; mt < 4; ++mt) {
            bf16x8 pa = *(const bf16x8*)&sP[(mt * 16 + l15) * PROW + ks * 32 + g * 8];
#pragma unroll
            for (int nt = 0; nt < 2; ++nt)
                oacc[mt][nt] = __builtin_amdgcn_mfma_f32_16x16x32_bf16(pa, bv[ks][nt], oacc[mt][nt], 0, 0, 0);
        }

    // ======== Phase 5: store (4x64B segments per instruction) ========
#pragma unroll
    for (int mt = 0; mt < 4; ++mt)
#pragma unroll
        for (int r = 0; r < 4; ++r) {
            int i = mt * 16 + g * 4 + r;
            if (i < NWIN) {
                float* op = out + base + (size_t)i * CCH + l15;
                op[0]  = oacc[mt][0][r];
                op[16] = oacc[mt][1][r];
            }
        }
}

extern "C" void kernel_launch(void* const* d_in, const int* in_sizes, int n_in,
                              void* d_out, int out_size, void* d_ws, size_t ws_size,
                              hipStream_t stream) {
    const float* q  = (const float*)d_in[0];
    const float* k  = (const float*)d_in[1];
    const float* v  = (const float*)d_in[2];
    const float* W1 = (const float*)d_in[3];
    const float* b1 = (const float*)d_in[4];
    const float* W2 = (const float*)d_in[5];
    const float* b2 = (const float*)d_in[6];

    float* pos   = (float*)d_ws;                       // 169*8 fp32
    float* bfrag = (float*)((char*)d_ws + 8192);       // 128*256 fp32 = 131072 B
    float* out   = (float*)d_out;

    const int B = in_sizes[0] / (NWIN * CCH);          // 2048

    pos_mlp_kernel<<<1, 192, 0, stream>>>(W1, b1, W2, b2, pos);
    bias_frag_kernel<<<128, 64, 0, stream>>>(pos, bfrag);
    attn_kernel<<<B * NH, 64, 0, stream>>>(q, k, v, bfrag, out);
}

// Round 7
// 113.681 us; speedup vs baseline: 1.2753x; 1.2753x over previous
//
#include <hip/hip_runtime.h>
#include <hip/hip_bf16.h>

typedef __attribute__((ext_vector_type(8))) short bf16x8;
typedef __attribute__((ext_vector_type(4))) float f32x4;

#define NWIN 49
#define NH 8
#define CCH 256
#define PROW 72   // ushort stride for P rows (144B, 16B-aligned)

__device__ __forceinline__ ushort2 pk_bf16(float a, float b) {
    __hip_bfloat162 t = __float22bfloat162_rn(float2{a, b});   // v_cvt_pk_bf16_f32 (RNE)
    return *(ushort2*)&t;
}
__device__ __forceinline__ float upk(ushort u) { return __uint_as_float((unsigned)u << 16); }

// --- Kernel A: pos MLP table, (169, 8) fp32 ---
__global__ void pos_mlp_kernel(const float* __restrict__ W1, const float* __restrict__ b1,
                               const float* __restrict__ W2, const float* __restrict__ b2,
                               float* __restrict__ pos) {
    int idx = blockIdx.x * blockDim.x + threadIdx.x;
    if (idx >= 169) return;
    float bh = (float)(idx / 13) - 6.0f;
    float bw = (float)(idx % 13) - 6.0f;
    float outv[NH];
#pragma unroll
    for (int t = 0; t < NH; ++t) outv[t] = b2[t];
    for (int u = 0; u < 64; ++u) {
        float hv = fmaf(bh, W1[u], fmaf(bw, W1[64 + u], b1[u]));
        hv = fmaxf(hv, 0.0f);
#pragma unroll
        for (int t = 0; t < NH; ++t) outv[t] = fmaf(hv, W2[u * NH + t], outv[t]);
    }
#pragma unroll
    for (int t = 0; t < NH; ++t) pos[idx * NH + t] = outv[t];
}

// --- Kernel B: bias (×log2e) in S^T MFMA C/D fragment layout, -1e30 mask for j>=49 ---
// bfrag[((h*4 + jt)*4 + it)*256 + lane*4 + r] = log2e*bias(i=it*16+(lane&15), j=jt*16+(lane>>4)*4+r)
__global__ void bias_frag_kernel(const float* __restrict__ pos, float* __restrict__ bfrag) {
    int blk = blockIdx.x;           // ((h*4 + jt)*4 + it), 128 blocks
    int it = blk & 3, jt = (blk >> 2) & 3, h = blk >> 4;
    int lane = threadIdx.x;
    int g = lane >> 4, l15 = lane & 15;
    int i = it * 16 + l15;
    float4 v;
    float* vp = (float*)&v;
#pragma unroll
    for (int r = 0; r < 4; ++r) {
        int j = jt * 16 + g * 4 + r;
        float val;
        if (j >= NWIN) val = -1e30f;                       // exp2 -> 0
        else if (i >= NWIN) val = 0.0f;
        else {
            int rel = (i / 7 - j / 7 + 6) * 13 + (i % 7 - j % 7 + 6);
            val = pos[rel * NH + h] * 1.4426950408889634f; // fold log2e
        }
        vp[r] = val;
    }
    *(float4*)(bfrag + (size_t)blk * 256 + lane * 4) = v;
}

// --- Kernel C: 4 waves per WG, each wave an INDEPENDENT (window, head) problem.
//     Per-wave body identical to round-5 (proven); no barriers, private sP region.
__global__ __launch_bounds__(256, 4) void attn_kernel(
    const float* __restrict__ q, const float* __restrict__ k,
    const float* __restrict__ v, const float* __restrict__ bfrag,
    float* __restrict__ out) {
    __shared__ __align__(16) ushort sP[4][64 * PROW];   // 36864 B

    const int tid = threadIdx.x;
    const int w = tid >> 6, lane = tid & 63;
    const int pidx = blockIdx.x * 4 + w;     // problem = (window, head)
    const int b = pidx >> 3, h = pidx & 7;
    const int g = lane >> 4, l15 = lane & 15;
    const size_t base = (size_t)b * (NWIN * CCH) + h * 32;
    ushort* myP = sP[w];

    // ---- K fragments (A-operand, rows j=t*16+l15, cols g*8..g*8+7), bf16 hi+lo ----
    // ---- Q fragments (B-operand, same lane->memory pattern), bf16 hi+lo        ----
    bf16x8 kah[4], kal[4], qbh[4], qbl[4];
#pragma unroll
    for (int t = 0; t < 4; ++t) {
        int row = t * 16 + l15;
        float4 ka = {0, 0, 0, 0}, kb = {0, 0, 0, 0};
        float4 qa = {0, 0, 0, 0}, qb = {0, 0, 0, 0};
        if (row < NWIN) {
            const float* kp = k + base + (size_t)row * CCH + g * 8;
            const float* qp = q + base + (size_t)row * CCH + g * 8;
            ka = *(const float4*)kp; kb = *(const float4*)(kp + 4);
            qa = *(const float4*)qp; qb = *(const float4*)(qp + 4);
        }
        ushort2 kh0 = pk_bf16(ka.x, ka.y), kh1 = pk_bf16(ka.z, ka.w);
        ushort2 kh2 = pk_bf16(kb.x, kb.y), kh3 = pk_bf16(kb.z, kb.w);
        ushort2 kl0 = pk_bf16(ka.x - upk(kh0.x), ka.y - upk(kh0.y));
        ushort2 kl1 = pk_bf16(ka.z - upk(kh1.x), ka.w - upk(kh1.y));
        ushort2 kl2 = pk_bf16(kb.x - upk(kh2.x), kb.y - upk(kh2.y));
        ushort2 kl3 = pk_bf16(kb.z - upk(kh3.x), kb.w - upk(kh3.y));
        ushort tkh[8] = {kh0.x, kh0.y, kh1.x, kh1.y, kh2.x, kh2.y, kh3.x, kh3.y};
        ushort tkl[8] = {kl0.x, kl0.y, kl1.x, kl1.y, kl2.x, kl2.y, kl3.x, kl3.y};
        kah[t] = *(bf16x8*)tkh; kal[t] = *(bf16x8*)tkl;
        ushort2 qh0 = pk_bf16(qa.x, qa.y), qh1 = pk_bf16(qa.z, qa.w);
        ushort2 qh2 = pk_bf16(qb.x, qb.y), qh3 = pk_bf16(qb.z, qb.w);
        ushort2 ql0 = pk_bf16(qa.x - upk(qh0.x), qa.y - upk(qh0.y));
        ushort2 ql1 = pk_bf16(qa.z - upk(qh1.x), qa.w - upk(qh1.y));
        ushort2 ql2 = pk_bf16(qb.x - upk(qh2.x), qb.y - upk(qh2.y));
        ushort2 ql3 = pk_bf16(qb.z - upk(qh3.x), qb.w - upk(qh3.y));
        ushort tqh[8] = {qh0.x, qh0.y, qh1.x, qh1.y, qh2.x, qh2.y, qh3.x, qh3.y};
        ushort tql[8] = {ql0.x, ql0.y, ql1.x, ql1.y, ql2.x, ql2.y, ql3.x, ql3.y};
        qbh[t] = *(bf16x8*)tqh; qbl[t] = *(bf16x8*)tql;
    }

    // ---- QK^T (swapped): acc[jt][it] = S^T tile; bf16x3 for fp32-accurate logits ----
    f32x4 acc[4][4];
#pragma unroll
    for (int jt = 0; jt < 4; ++jt)
#pragma unroll
        for (int it = 0; it < 4; ++it) {
            f32x4 a = {0.f, 0.f, 0.f, 0.f};
            a = __builtin_amdgcn_mfma_f32_16x16x32_bf16(kah[jt], qbh[it], a, 0, 0, 0);
            a = __builtin_amdgcn_mfma_f32_16x16x32_bf16(kah[jt], qbl[it], a, 0, 0, 0);
            a = __builtin_amdgcn_mfma_f32_16x16x32_bf16(kal[jt], qbh[it], a, 0, 0, 0);
            acc[jt][it] = a;
        }

    // ---- softmax per column i (no max-sub: |logits| bounded; table holds log2e*bias) ----
    const float scale2 = 0.17677669529663687f * 1.4426950408889634f;
#pragma unroll
    for (int it = 0; it < 4; ++it) {
        float p[16];
        float s = 0.0f;
#pragma unroll
        for (int jt = 0; jt < 4; ++jt) {
            f32x4 bb = *(const f32x4*)(bfrag + (size_t)((h * 4 + jt) * 4 + it) * 256 + lane * 4);
#pragma unroll
            for (int r = 0; r < 4; ++r) {
                float e = __builtin_amdgcn_exp2f(fmaf(acc[jt][it][r], scale2, bb[r]));
                p[jt * 4 + r] = e;
                s += e;
            }
        }
        s += __shfl_xor(s, 16);
        s += __shfl_xor(s, 32);
        const float inv = 1.0f / s;
#pragma unroll
        for (int jt = 0; jt < 4; ++jt) {
            ushort2 a01 = pk_bf16(p[jt * 4 + 0] * inv, p[jt * 4 + 1] * inv);
            ushort2 a23 = pk_bf16(p[jt * 4 + 2] * inv, p[jt * 4 + 3] * inv);
            ushort4 w4; w4.x = a01.x; w4.y = a01.y; w4.z = a23.x; w4.w = a23.y;
            *(ushort4*)&myP[(it * 16 + l15) * PROW + jt * 16 + g * 4] = w4;
        }
    }

    // ---- V B-fragments direct from global (rows j=ks*32+g*8+e, col d=nt*16+l15) ----
    bf16x8 bv[2][2];
#pragma unroll
    for (int ks = 0; ks < 2; ++ks)
#pragma unroll
        for (int nt = 0; nt < 2; ++nt) {
            float vv[8];
#pragma unroll
            for (int e = 0; e < 8; ++e) {
                int j = ks * 32 + g * 8 + e;
                vv[e] = (j < NWIN) ? v[base + (size_t)j * CCH + nt * 16 + l15] : 0.0f;
            }
            ushort2 p0 = pk_bf16(vv[0], vv[1]), p1 = pk_bf16(vv[2], vv[3]);
            ushort2 p2 = pk_bf16(vv[4], vv[5]), p3 = pk_bf16(vv[6], vv[7]);
            ushort tv[8] = {p0.x, p0.y, p1.x, p1.y, p2.x, p2.y, p3.x, p3.y};
            bv[ks][nt] = *(bf16x8*)tv;
        }

    // ---- PV (P A-frags from private LDS; same-wave write->read, no barrier) ----
    f32x4 oacc[4][2];
#pragma unroll
    for (int mt = 0; mt < 4; ++mt)
#pragma unroll
        for (int nt = 0; nt < 2; ++nt) oacc[mt][nt] = (f32x4){0.f, 0.f, 0.f, 0.f};
#pragma unroll
    for (int ks = 0; ks < 2; ++ks)
#pragma unroll
        for (int mt = 0; mt < 4; ++mt) {
            bf16x8 pa = *(const bf16x8*)&myP[(mt * 16 + l15) * PROW + ks * 32 + g * 8];
#pragma unroll
            for (int nt = 0; nt < 2; ++nt)
                oacc[mt][nt] = __builtin_amdgcn_mfma_f32_16x16x32_bf16(pa, bv[ks][nt], oacc[mt][nt], 0, 0, 0);
        }

    // ---- store (lane pattern: 4x 64B segments per instruction) ----
#pragma unroll
    for (int mt = 0; mt < 4; ++mt)
#pragma unroll
        for (int r = 0; r < 4; ++r) {
            int i = mt * 16 + g * 4 + r;
            if (i < NWIN) {
                float* op = out + base + (size_t)i * CCH + l15;
                op[0]  = oacc[mt][0][r];
                op[16] = oacc[mt][1][r];
            }
        }
}

extern "C" void kernel_launch(void* const* d_in, const int* in_sizes, int n_in,
                              void* d_out, int out_size, void* d_ws, size_t ws_size,
                              hipStream_t stream) {
    const float* q  = (const float*)d_in[0];
    const float* k  = (const float*)d_in[1];
    const float* v  = (const float*)d_in[2];
    const float* W1 = (const float*)d_in[3];
    const float* b1 = (const float*)d_in[4];
    const float* W2 = (const float*)d_in[5];
    const float* b2 = (const float*)d_in[6];

    float* pos   = (float*)d_ws;                       // 169*8 fp32
    float* bfrag = (float*)((char*)d_ws + 8192);       // 128*256 fp32 = 131072 B
    float* out   = (float*)d_out;

    const int B = in_sizes[0] / (NWIN * CCH);          // 2048

    pos_mlp_kernel<<<1, 192, 0, stream>>>(W1, b1, W2, b2, pos);
    bias_frag_kernel<<<128, 64, 0, stream>>>(pos, bfrag);
    attn_kernel<<<(B * NH) / 4, 256, 0, stream>>>(q, k, v, bfrag, out);
}

// Round 8
// 105.070 us; speedup vs baseline: 1.3798x; 1.0820x over previous
//
#include <hip/hip_runtime.h>
#include <hip/hip_bf16.h>

typedef __attribute__((ext_vector_type(8))) short bf16x8;
typedef __attribute__((ext_vector_type(4))) float f32x4;

#define NWIN 49
#define NH 8
#define CCH 256
#define PROW 72   // ushort stride for P rows (144B, 16B-aligned)

__device__ __forceinline__ ushort2 pk_bf16(float a, float b) {
    __hip_bfloat162 t = __float22bfloat162_rn(float2{a, b});   // v_cvt_pk_bf16_f32 (RNE)
    return *(ushort2*)&t;
}
__device__ __forceinline__ float upk(ushort u) { return __uint_as_float((unsigned)u << 16); }

// --- Kernel A: pos MLP table, (169, 8) fp32 ---
__global__ void pos_mlp_kernel(const float* __restrict__ W1, const float* __restrict__ b1,
                               const float* __restrict__ W2, const float* __restrict__ b2,
                               float* __restrict__ pos) {
    int idx = blockIdx.x * blockDim.x + threadIdx.x;
    if (idx >= 169) return;
    float bh = (float)(idx / 13) - 6.0f;
    float bw = (float)(idx % 13) - 6.0f;
    float outv[NH];
#pragma unroll
    for (int t = 0; t < NH; ++t) outv[t] = b2[t];
    for (int u = 0; u < 64; ++u) {
        float hv = fmaf(bh, W1[u], fmaf(bw, W1[64 + u], b1[u]));
        hv = fmaxf(hv, 0.0f);
#pragma unroll
        for (int t = 0; t < NH; ++t) outv[t] = fmaf(hv, W2[u * NH + t], outv[t]);
    }
#pragma unroll
    for (int t = 0; t < NH; ++t) pos[idx * NH + t] = outv[t];
}

// --- Kernel B: bias (×log2e) in S^T MFMA C/D fragment layout, -1e30 mask for j>=49 ---
// bfrag[((h*4 + jt)*4 + it)*256 + lane*4 + r] = log2e*bias(i=it*16+(lane&15), j=jt*16+(lane>>4)*4+r)
__global__ void bias_frag_kernel(const float* __restrict__ pos, float* __restrict__ bfrag) {
    int blk = blockIdx.x;           // ((h*4 + jt)*4 + it), 128 blocks
    int it = blk & 3, jt = (blk >> 2) & 3, h = blk >> 4;
    int lane = threadIdx.x;
    int g = lane >> 4, l15 = lane & 15;
    int i = it * 16 + l15;
    float4 v;
    float* vp = (float*)&v;
#pragma unroll
    for (int r = 0; r < 4; ++r) {
        int j = jt * 16 + g * 4 + r;
        float val;
        if (j >= NWIN) val = -1e30f;                       // exp2 -> 0 (kills clamped K rows)
        else if (i >= NWIN) val = 0.0f;
        else {
            int rel = (i / 7 - j / 7 + 6) * 13 + (i % 7 - j % 7 + 6);
            val = pos[rel * NH + h] * 1.4426950408889634f; // fold log2e
        }
        vp[r] = val;
    }
    *(float4*)(bfrag + (size_t)blk * 256 + lane * 4) = v;
}

// --- Kernel C: 512 threads = 8 waves = ALL 8 heads of ONE window.
//     Wave w = head w; per-wave body identical to round-7 (clamped addressing).
//     WG-synchronized loads cover full 1KB rows -> DRAM-burst-efficient.
__global__ __launch_bounds__(512, 4) void attn_kernel(
    const float* __restrict__ q, const float* __restrict__ k,
    const float* __restrict__ v, const float* __restrict__ bfrag,
    float* __restrict__ out) {
    __shared__ __align__(16) ushort sP[8][64 * PROW];   // 73728 B -> 2 WG/CU

    // Bijective XCD swizzle: gridDim.x = 2048 (2048 % 8 == 0), each XCD gets a
    // contiguous window range -> sequential 50KB slabs per XCD L2.
    const int nper = (int)(gridDim.x >> 3);
    const int b = ((int)blockIdx.x & 7) * nper + ((int)blockIdx.x >> 3);

    const int tid = threadIdx.x;
    const int w = tid >> 6, lane = tid & 63;   // w = head
    const int h = w;
    const int g = lane >> 4, l15 = lane & 15;
    const size_t base = (size_t)b * (NWIN * CCH) + h * 32;
    ushort* myP = sP[w];

    // ---- K fragments (A-operand, rows j=t*16+l15, cols g*8..g*8+7), bf16 hi+lo ----
    // ---- Q fragments (B-operand, same lane->memory pattern), bf16 hi+lo        ----
    // Rows >= 49 clamped to 48: K-garbage killed by -1e30 bias, Q-garbage never stored.
    bf16x8 kah[4], kal[4], qbh[4], qbl[4];
#pragma unroll
    for (int t = 0; t < 4; ++t) {
        int row = t * 16 + l15;
        int rc = row < NWIN ? row : NWIN - 1;
        const float* kp = k + base + (size_t)rc * CCH + g * 8;
        const float* qp = q + base + (size_t)rc * CCH + g * 8;
        float4 ka = *(const float4*)kp, kb = *(const float4*)(kp + 4);
        float4 qa = *(const float4*)qp, qb = *(const float4*)(qp + 4);
        ushort2 kh0 = pk_bf16(ka.x, ka.y), kh1 = pk_bf16(ka.z, ka.w);
        ushort2 kh2 = pk_bf16(kb.x, kb.y), kh3 = pk_bf16(kb.z, kb.w);
        ushort2 kl0 = pk_bf16(ka.x - upk(kh0.x), ka.y - upk(kh0.y));
        ushort2 kl1 = pk_bf16(ka.z - upk(kh1.x), ka.w - upk(kh1.y));
        ushort2 kl2 = pk_bf16(kb.x - upk(kh2.x), kb.y - upk(kh2.y));
        ushort2 kl3 = pk_bf16(kb.z - upk(kh3.x), kb.w - upk(kh3.y));
        ushort tkh[8] = {kh0.x, kh0.y, kh1.x, kh1.y, kh2.x, kh2.y, kh3.x, kh3.y};
        ushort tkl[8] = {kl0.x, kl0.y, kl1.x, kl1.y, kl2.x, kl2.y, kl3.x, kl3.y};
        kah[t] = *(bf16x8*)tkh; kal[t] = *(bf16x8*)tkl;
        ushort2 qh0 = pk_bf16(qa.x, qa.y), qh1 = pk_bf16(qa.z, qa.w);
        ushort2 qh2 = pk_bf16(qb.x, qb.y), qh3 = pk_bf16(qb.z, qb.w);
        ushort2 ql0 = pk_bf16(qa.x - upk(qh0.x), qa.y - upk(qh0.y));
        ushort2 ql1 = pk_bf16(qa.z - upk(qh1.x), qa.w - upk(qh1.y));
        ushort2 ql2 = pk_bf16(qb.x - upk(qh2.x), qb.y - upk(qh2.y));
        ushort2 ql3 = pk_bf16(qb.z - upk(qh3.x), qb.w - upk(qh3.y));
        ushort tqh[8] = {qh0.x, qh0.y, qh1.x, qh1.y, qh2.x, qh2.y, qh3.x, qh3.y};
        ushort tql[8] = {ql0.x, ql0.y, ql1.x, ql1.y, ql2.x, ql2.y, ql3.x, ql3.y};
        qbh[t] = *(bf16x8*)tqh; qbl[t] = *(bf16x8*)tql;
    }

    // ---- QK^T (swapped): acc[jt][it] = S^T tile; bf16x3 for fp32-accurate logits ----
    f32x4 acc[4][4];
#pragma unroll
    for (int jt = 0; jt < 4; ++jt)
#pragma unroll
        for (int it = 0; it < 4; ++it) {
            f32x4 a = {0.f, 0.f, 0.f, 0.f};
            a = __builtin_amdgcn_mfma_f32_16x16x32_bf16(kah[jt], qbh[it], a, 0, 0, 0);
            a = __builtin_amdgcn_mfma_f32_16x16x32_bf16(kah[jt], qbl[it], a, 0, 0, 0);
            a = __builtin_amdgcn_mfma_f32_16x16x32_bf16(kal[jt], qbh[it], a, 0, 0, 0);
            acc[jt][it] = a;
        }

    // ---- softmax per column i (no max-sub: |logits| bounded; table holds log2e*bias) ----
    const float scale2 = 0.17677669529663687f * 1.4426950408889634f;
#pragma unroll
    for (int it = 0; it < 4; ++it) {
        float p[16];
        float s = 0.0f;
#pragma unroll
        for (int jt = 0; jt < 4; ++jt) {
            f32x4 bb = *(const f32x4*)(bfrag + (size_t)((h * 4 + jt) * 4 + it) * 256 + lane * 4);
#pragma unroll
            for (int r = 0; r < 4; ++r) {
                float e = __builtin_amdgcn_exp2f(fmaf(acc[jt][it][r], scale2, bb[r]));
                p[jt * 4 + r] = e;
                s += e;
            }
        }
        s += __shfl_xor(s, 16);
        s += __shfl_xor(s, 32);
        const float inv = 1.0f / s;
#pragma unroll
        for (int jt = 0; jt < 4; ++jt) {
            ushort2 a01 = pk_bf16(p[jt * 4 + 0] * inv, p[jt * 4 + 1] * inv);
            ushort2 a23 = pk_bf16(p[jt * 4 + 2] * inv, p[jt * 4 + 3] * inv);
            ushort4 w4; w4.x = a01.x; w4.y = a01.y; w4.z = a23.x; w4.w = a23.y;
            *(ushort4*)&myP[(it * 16 + l15) * PROW + jt * 16 + g * 4] = w4;
        }
    }

    // ---- V B-fragments direct from global (rows j=ks*32+g*8+e clamped, col d=nt*16+l15) ----
    bf16x8 bv[2][2];
#pragma unroll
    for (int ks = 0; ks < 2; ++ks)
#pragma unroll
        for (int nt = 0; nt < 2; ++nt) {
            float vv[8];
#pragma unroll
            for (int e = 0; e < 8; ++e) {
                int j = ks * 32 + g * 8 + e;
                int jc = j < NWIN ? j : NWIN - 1;   // P[j>=49]=0, so clamped data contributes 0
                vv[e] = v[base + (size_t)jc * CCH + nt * 16 + l15];
            }
            ushort2 p0 = pk_bf16(vv[0], vv[1]), p1 = pk_bf16(vv[2], vv[3]);
            ushort2 p2 = pk_bf16(vv[4], vv[5]), p3 = pk_bf16(vv[6], vv[7]);
            ushort tv[8] = {p0.x, p0.y, p1.x, p1.y, p2.x, p2.y, p3.x, p3.y};
            bv[ks][nt] = *(bf16x8*)tv;
        }

    // ---- PV (P A-frags from private LDS; same-wave write->read, no barrier) ----
    f32x4 oacc[4][2];
#pragma unroll
    for (int mt = 0; mt < 4; ++mt)
#pragma unroll
        for (int nt = 0; nt < 2; ++nt) oacc[mt][nt] = (f32x4){0.f, 0.f, 0.f, 0.f};
#pragma unroll
    for (int ks = 0; ks < 2; ++ks)
#pragma unroll
        for (int mt = 0; mt < 4; ++mt) {
            bf16x8 pa = *(const bf16x8*)&myP[(mt * 16 + l15) * PROW + ks * 32 + g * 8];
#pragma unroll
            for (int nt = 0; nt < 2; ++nt)
                oacc[mt][nt] = __builtin_amdgcn_mfma_f32_16x16x32_bf16(pa, bv[ks][nt], oacc[mt][nt], 0, 0, 0);
        }

    // ---- store (lane pattern: 4x 64B segments per instruction; 8 waves cover full rows) ----
#pragma unroll
    for (int mt = 0; mt < 4; ++mt)
#pragma unroll
        for (int r = 0; r < 4; ++r) {
            int i = mt * 16 + g * 4 + r;
            if (i < NWIN) {
                float* op = out + base + (size_t)i * CCH + l15;
                op[0]  = oacc[mt][0][r];
                op[16] = oacc[mt][1][r];
            }
        }
}

extern "C" void kernel_launch(void* const* d_in, const int* in_sizes, int n_in,
                              void* d_out, int out_size, void* d_ws, size_t ws_size,
                              hipStream_t stream) {
    const float* q  = (const float*)d_in[0];
    const float* k  = (const float*)d_in[1];
    const float* v  = (const float*)d_in[2];
    const float* W1 = (const float*)d_in[3];
    const float* b1 = (const float*)d_in[4];
    const float* W2 = (const float*)d_in[5];
    const float* b2 = (const float*)d_in[6];

    float* pos   = (float*)d_ws;                       // 169*8 fp32
    float* bfrag = (float*)((char*)d_ws + 8192);       // 128*256 fp32 = 131072 B
    float* out   = (float*)d_out;

    const int B = in_sizes[0] / (NWIN * CCH);          // 2048 (divisible by 8)

    pos_mlp_kernel<<<1, 192, 0, stream>>>(W1, b1, W2, b2, pos);
    bias_frag_kernel<<<128, 64, 0, stream>>>(pos, bfrag);
    attn_kernel<<<B, 512, 0, stream>>>(q, k, v, bfrag, out);
}